// Round 7
// baseline (26543.524 us; speedup 1.0000x reference)
//
#include <hip/hip_runtime.h>
#include <math.h>

// Problem constants
#define TT    12288            // B*S flattened scan length
#define HH    600
#define GG    1800             // 3*H
#define INP   303
#define INP_P 304              // padded for float4 alignment
#define BB    32
#define SS    384
#define D2    1200             // 2H
#define D4    2400             // 4H (cat dim)

// Scan partitioning: 75 workgroups per chain, 8 outputs each
#define NWG  75
#define JPW  8
#define WROW 608               // LDS row pad: 608 % 32 == 0 -> row base bank 0

#define SENT   0xAAAAAAAAu
#define SENT64 0xAAAAAAAAAAAAAAAAull

// ws layout (float offsets)
#define EMB_OFF    0ull                // also reused as P_OFF after gemm_gi consumes emb
#define WP_OFF     3735552ull          // 12288*304
#define GI_OFF     4282752ull          // + 1800*304
#define HS_OFF     26403808ull
#define Q_OFF      26442208ull
#define CTX_OFF    26480608ull
#define GATED_OFF  26519008ull
#define COUNT_OFF  26557408ull         // 2 chains * 8 counters * 64-u32 stride
#define P_OFF      0ull                // probs (32*384) — emb region is dead by then

// ---------------- K0: build padded emb = [bio_emb[tag], context], and padded W_ih
__global__ void build_emb(const float* __restrict__ ctx, const int* __restrict__ tags,
                          const float* __restrict__ bio, float* __restrict__ emb) {
    int idx = blockIdx.x * 256 + threadIdx.x;
    if (idx >= TT * INP_P) return;
    int row = idx / INP_P;
    int c = idx - row * INP_P;
    float v;
    if (c < 3)        v = bio[tags[row] * 3 + c];
    else if (c < INP) v = ctx[(size_t)row * 300 + (c - 3)];
    else              v = 0.f;
    emb[idx] = v;
}

__global__ void pad_wih(const float* __restrict__ W, float* __restrict__ Wp) {
    int idx = blockIdx.x * 256 + threadIdx.x;
    if (idx >= GG * INP_P) return;
    int r = idx / INP_P, c = idx - r * INP_P;
    Wp[idx] = (c < INP) ? W[(size_t)r * INP + c] : 0.f;
}

// ---------------- K1: gi = emb @ W_ih^T + b_ih   (fp32 tiled GEMM, 64x64 tile, BK=16)
__global__ __launch_bounds__(256) void gemm_gi(const float* __restrict__ A,
                                               const float* __restrict__ Bw,
                                               const float* __restrict__ bias,
                                               float* __restrict__ C) {
    __shared__ float As[16][68];
    __shared__ float Bs[16][68];
    const int tid = threadIdx.x;
    const int bm = blockIdx.x, bn = blockIdx.y;
    const int tx = tid & 15, ty = tid >> 4;
    const int lm = tid >> 2;          // 0..63
    const int lk = (tid & 3) * 4;     // 0,4,8,12
    const int gbase = bn * 64;
    float acc[4][4] = {};
    for (int k0 = 0; k0 < INP_P; k0 += 16) {
        float4 av = *(const float4*)(A + (size_t)(bm * 64 + lm) * INP_P + k0 + lk);
        int grow = gbase + lm;
        float4 bv = make_float4(0.f, 0.f, 0.f, 0.f);
        if (grow < GG) bv = *(const float4*)(Bw + (size_t)grow * INP_P + k0 + lk);
        As[lk + 0][lm] = av.x; As[lk + 1][lm] = av.y; As[lk + 2][lm] = av.z; As[lk + 3][lm] = av.w;
        Bs[lk + 0][lm] = bv.x; Bs[lk + 1][lm] = bv.y; Bs[lk + 2][lm] = bv.z; Bs[lk + 3][lm] = bv.w;
        __syncthreads();
#pragma unroll
        for (int kk = 0; kk < 16; ++kk) {
            float4 a4 = *(const float4*)&As[kk][tx * 4];
            float4 b4 = *(const float4*)&Bs[kk][ty * 4];
            acc[0][0] += a4.x * b4.x; acc[0][1] += a4.x * b4.y; acc[0][2] += a4.x * b4.z; acc[0][3] += a4.x * b4.w;
            acc[1][0] += a4.y * b4.x; acc[1][1] += a4.y * b4.y; acc[1][2] += a4.y * b4.z; acc[1][3] += a4.y * b4.w;
            acc[2][0] += a4.z * b4.x; acc[2][1] += a4.z * b4.y; acc[2][2] += a4.z * b4.z; acc[2][3] += a4.z * b4.w;
            acc[3][0] += a4.w * b4.x; acc[3][1] += a4.w * b4.y; acc[3][2] += a4.w * b4.z; acc[3][3] += a4.w * b4.w;
        }
        __syncthreads();
    }
    int g0 = gbase + ty * 4;
    if (g0 < GG) {
        float4 bi4 = *(const float4*)(bias + g0);
#pragma unroll
        for (int i = 0; i < 4; ++i) {
            float4 v = make_float4(acc[i][0] + bi4.x, acc[i][1] + bi4.y,
                                   acc[i][2] + bi4.z, acc[i][3] + bi4.w);
            *(float4*)(C + (size_t)(bm * 64 + tx * 4 + i) * GG + g0) = v;
        }
    }
}

// ---------------- K2: the two sequential GRU scans.
// Sync = write-once sentinel (ground truth) + per-chain 8 sub-counters as a
// low-traffic readiness gate. WAVE-UNIFORM gate (round-6 deadlock fix):
// wave 0 ballot-polls the counters (lane l<8 checks counter l, others true;
// loop condition is the full-wave ballot -> no divergent cross-lane spin),
// then lane 0 releases waves 1-2 via an LDS flag. Staging lanes burst-load h
// once; sentinel re-check makes counter/visibility races benign. One
// barrier/step; h double-buffered; gi pipelined; weights in bank-aligned LDS.
__global__ __launch_bounds__(256) void gru_scan(const float* __restrict__ gi,
                                                const float* __restrict__ Whh,
                                                const float* __restrict__ bhh,
                                                float* __restrict__ ws,
                                                float* __restrict__ out) {
    __shared__ __align__(16) float w_lds[JPW * 3 * WROW];   // 58,368 B
    __shared__ __align__(16) float h_lds[2][WROW];          //  4,864 B
    __shared__ unsigned go_lds;

    const int tid = threadIdx.x;
    const int chain = blockIdx.x / NWG;   // 0 = fwd, 1 = bwd
    const int wg = blockIdx.x % NWG;
    const int j0 = wg * JPW;
    const int wave = tid >> 6;
    const int lane = tid & 63;
    const int half = lane >> 5;
    const int s = lane & 31;              // sub-lane within 32-lane group
    const int j = wave * 2 + half;        // output 0..7 within wg
    const int jg = j0 + j;                // global hidden index

    float* statesOut = out + 1200 + (size_t)chain * TT * 600;
    unsigned long long* statesU64 = (unsigned long long*)statesOut;
    unsigned* cnt = (unsigned*)(ws + COUNT_OFF) + (size_t)chain * 512;  // 8 x 64-u32 stride
    const unsigned cntk = (lane < 3) ? 10u : 9u;   // #wgs with wg%8==lane (75 = 3*10 + 5*9)

    // ---- one-time: W_hh slice into LDS. w_lds[(j*3+g)*WROW + c]
    for (int q = tid; q < JPW * 3 * 150; q += 256) {   // 150 float4 per row
        int row = q / 150, c4 = (q - row * 150) * 4;
        int jj = row / 3, g = row - jj * 3;
        *(float4*)&w_lds[row * WROW + c4] =
            *(const float4*)(Whh + (size_t)(g * 600 + j0 + jj) * 600 + c4);
    }
    float b_r = 0.f, b_z = 0.f, b_n = 0.f;
    if (s == 0) { b_r = bhh[jg]; b_z = bhh[600 + jg]; b_n = bhh[1200 + jg]; }
    for (int i = tid; i < 2 * WROW; i += 256) h_lds[0][i] = 0.f;
    if (tid == 0) go_lds = 0u;
    __syncthreads();

    // gi pipeline: load row(0) now, issue row(t+1) inside the loop
    float gr_c = 0.f, gz_c = 0.f, gn_c = 0.f;
    int si = 0, bi = 0;
    if (s == 0) {
        int r0 = (chain == 0) ? 0 : (SS - 1);
        const float* gp = gi + (size_t)r0 * GG + jg;
        gr_c = gp[0]; gz_c = gp[600]; gn_c = gp[1200];
    }

    float h_own = 0.f;                    // h_{t-1}[jg], kept by s==0 lanes

    for (int t = 0; t < TT; ++t) {
        const int slot = t & 1;
        if (t > 0) {
            if (wave == 0) {
                // wave-uniform readiness gate: ballot over all 64 lanes
                const unsigned tgt = (unsigned)t * cntk;
                for (;;) {
                    bool ok = true;
                    if (lane < 8)
                        ok = __hip_atomic_load(cnt + lane * 64, __ATOMIC_RELAXED,
                                               __HIP_MEMORY_SCOPE_AGENT) >= tgt;
                    if (__ballot(ok) == ~0ull) break;
                    __builtin_amdgcn_s_sleep(1);
                }
                if (lane == 0)
                    __hip_atomic_store(&go_lds, (unsigned)t, __ATOMIC_RELAXED,
                                       __HIP_MEMORY_SCOPE_WORKGROUP);
            } else if (wave <= 2) {
                // whole waves 1 and 2 wait on the LDS flag (setter is wave 0)
                while (__hip_atomic_load(&go_lds, __ATOMIC_RELAXED,
                                         __HIP_MEMORY_SCOPE_WORKGROUP) < (unsigned)t) {}
            }
            if (tid < 150) {
                // burst h load (normally one sweep; sentinel = ground truth)
                const unsigned long long* hu = statesU64 + (size_t)(t - 1) * 300 + tid * 2;
                unsigned long long u0 = __hip_atomic_load(hu + 0, __ATOMIC_RELAXED, __HIP_MEMORY_SCOPE_AGENT);
                unsigned long long u1 = __hip_atomic_load(hu + 1, __ATOMIC_RELAXED, __HIP_MEMORY_SCOPE_AGENT);
                while (u0 == SENT64 || u1 == SENT64) {
                    u0 = __hip_atomic_load(hu + 0, __ATOMIC_RELAXED, __HIP_MEMORY_SCOPE_AGENT);
                    u1 = __hip_atomic_load(hu + 1, __ATOMIC_RELAXED, __HIP_MEMORY_SCOPE_AGENT);
                }
                float4 hv;
                ((unsigned long long*)&hv)[0] = u0;
                ((unsigned long long*)&hv)[1] = u1;
                *(float4*)&h_lds[slot][tid * 4] = hv;
            }
            __syncthreads();              // the ONLY barrier per step
        }
        // issue next step's gi loads (consumed next iteration)
        float gr_n = gr_c, gz_n = gz_c, gn_n = gn_c;
        int si2 = si + 1, bi2 = bi;
        if (si2 == SS) { si2 = 0; ++bi2; }
        if (s == 0 && t + 1 < TT) {
            int rn = (chain == 0) ? (t + 1) : (bi2 * SS + (SS - 1) - si2);
            const float* gp = gi + (size_t)rn * GG + jg;
            gr_n = gp[0]; gz_n = gp[600]; gn_n = gp[1200];
        }
        // matvec: rows {j, 600+j, 1200+j}, lane s covers cols [20s, 20s+20)
        float a0 = 0.f, a1 = 0.f, a2 = 0.f;
        if (s < 30) {
            const float* w0 = &w_lds[(j * 3 + 0) * WROW + s * 20];
            const float* w1 = &w_lds[(j * 3 + 1) * WROW + s * 20];
            const float* w2 = &w_lds[(j * 3 + 2) * WROW + s * 20];
            const float* hp = &h_lds[slot][s * 20];
#pragma unroll
            for (int u = 0; u < 5; ++u) {
                float4 hv = *(const float4*)(hp + u * 4);
                float4 x0 = *(const float4*)(w0 + u * 4);
                float4 x1 = *(const float4*)(w1 + u * 4);
                float4 x2 = *(const float4*)(w2 + u * 4);
                a0 += x0.x * hv.x + x0.y * hv.y + x0.z * hv.z + x0.w * hv.w;
                a1 += x1.x * hv.x + x1.y * hv.y + x1.z * hv.z + x1.w * hv.w;
                a2 += x2.x * hv.x + x2.y * hv.y + x2.z * hv.z + x2.w * hv.w;
            }
        }
#pragma unroll
        for (int off = 16; off > 0; off >>= 1) {
            a0 += __shfl_down(a0, off, 32);
            a1 += __shfl_down(a1, off, 32);
            a2 += __shfl_down(a2, off, 32);
        }
        if (s == 0) {
            float r = 1.f / (1.f + __expf(-(gr_c + a0 + b_r)));
            float z = 1.f / (1.f + __expf(-(gz_c + a1 + b_z)));
            float x = gn_c + r * (a2 + b_n);
            float e = __expf(-2.f * fabsf(x));
            float n = copysignf((1.f - e) / (1.f + e), x);
            float hnew = (1.f - z) * n + z * h_own;
            h_own = hnew;
            // pair with the other half-wave's output (j even <-> j odd)
            float partner = __shfl(hnew, (lane + 32) & 63);
            if (half == 0) {   // lane 0 of the wave stores the 8B pair
                unsigned long long pk = ((unsigned long long)__float_as_uint(hnew)) |
                                        (((unsigned long long)__float_as_uint(partner)) << 32);
                if (pk == SENT64) pk ^= 1ull;
                __hip_atomic_store(statesU64 + (size_t)t * 300 + (j0 >> 1) + wave, pk,
                                   __ATOMIC_RELAXED, __HIP_MEMORY_SCOPE_AGENT);
            }
            if (t == TT - 1) out[chain * 600 + jg] = hnew;   // final = [h_f, h_b]
        }
        // publish readiness (stragglers are caught by the sentinel re-poll)
        if (tid == 0)
            __hip_atomic_fetch_add(cnt + (wg & 7) * 64, 1u,
                                   __ATOMIC_RELAXED, __HIP_MEMORY_SCOPE_AGENT);
        gr_c = gr_n; gz_c = gz_n; gn_c = gn_n;
        si = si2; bi = bi2;
    }
}

// ---------------- K3a: hs gather + q = hs @ W_lin^T + b_lin  (grid 32 x 20)
__global__ __launch_bounds__(256) void attn_qs(const float* __restrict__ Wlin,
                                               const float* __restrict__ blin,
                                               const float* __restrict__ outp,
                                               float* __restrict__ ws) {
    __shared__ float hs_lds[1200];
    const int bi = blockIdx.x, ob = blockIdx.y * 60, tid = threadIdx.x;
    const float* fwdS = outp + 1200;
    const float* bwdS = outp + 1200 + (size_t)TT * 600;
    size_t row = (size_t)(bi * SS + SS - 1) * 600;
    for (int k = tid; k < 600; k += 256) {
        hs_lds[k] = fwdS[row + k];
        hs_lds[600 + k] = bwdS[row + k];
    }
    __syncthreads();
    if (blockIdx.y == 0) {
        float* ws_hs = ws + HS_OFF;
        for (int k = tid; k < 1200; k += 256) ws_hs[bi * 1200 + k] = hs_lds[k];
    }
    float* ws_q = ws + Q_OFF;
    const int wave = tid >> 6, lane = tid & 63;
    for (int i = 0; i < 15; ++i) {
        int o = ob + wave * 15 + i;
        const float* wr = Wlin + (size_t)o * 1200;
        float acc = 0.f;
        for (int k = lane; k < 1200; k += 64) acc += hs_lds[k] * wr[k];
        for (int off = 32; off > 0; off >>= 1) acc += __shfl_down(acc, off);
        if (lane == 0) ws_q[bi * 1200 + o] = acc + blin[o];
    }
}

// ---------------- K3b: logits + softmax -> probs
__global__ __launch_bounds__(256) void attn_logits(const float* __restrict__ outp,
                                                   float* __restrict__ ws) {
    __shared__ float q_lds[1200];
    __shared__ float p_lds[SS];
    __shared__ float red[8];
    const int bi = blockIdx.x, tid = threadIdx.x;
    const float* fwdS = outp + 1200;
    const float* bwdS = outp + 1200 + (size_t)TT * 600;
    const float* ws_q = ws + Q_OFF;
    for (int k = tid; k < 1200; k += 256) q_lds[k] = ws_q[bi * 1200 + k];
    __syncthreads();
    const int wave = tid >> 6, lane = tid & 63;
    for (int s = wave; s < SS; s += 4) {
        size_t base = (size_t)(bi * SS + s) * 600;
        float acc = 0.f;
        for (int k = lane; k < 600; k += 64)
            acc += q_lds[k] * fwdS[base + k] + q_lds[600 + k] * bwdS[base + k];
        for (int off = 32; off > 0; off >>= 1) acc += __shfl_down(acc, off);
        if (lane == 0) p_lds[s] = acc;
    }
    __syncthreads();
    float m = -1e30f;
    for (int i = tid; i < SS; i += 256) m = fmaxf(m, p_lds[i]);
    for (int off = 32; off > 0; off >>= 1) m = fmaxf(m, __shfl_down(m, off));
    if (lane == 0) red[wave] = m;
    __syncthreads();
    m = fmaxf(fmaxf(red[0], red[1]), fmaxf(red[2], red[3]));
    float ssum = 0.f;
    for (int i = tid; i < SS; i += 256) ssum += expf(p_lds[i] - m);
    for (int off = 32; off > 0; off >>= 1) ssum += __shfl_down(ssum, off);
    __syncthreads();
    if (lane == 0) red[wave] = ssum;
    __syncthreads();
    ssum = red[0] + red[1] + red[2] + red[3];
    float inv = 1.f / ssum;
    float* ws_p = ws + P_OFF;
    for (int i = tid; i < SS; i += 256) ws_p[bi * SS + i] = expf(p_lds[i] - m) * inv;
}

// ---------------- K3c: ctx = probs @ states  (grid 32 x 5, 240 threads active)
__global__ __launch_bounds__(256) void attn_ctxv(const float* __restrict__ outp,
                                                 float* __restrict__ ws) {
    __shared__ float p_lds[SS];
    const int bi = blockIdx.x, d0 = blockIdx.y * 240, tid = threadIdx.x;
    const float* ws_p = ws + P_OFF;
    for (int k = tid; k < SS; k += 256) p_lds[k] = ws_p[bi * SS + k];
    __syncthreads();
    if (tid >= 240) return;
    const int d = d0 + tid;
    const float* fwdS = outp + 1200;
    const float* bwdS = outp + 1200 + (size_t)TT * 600;
    const float* Sb = (d < 600) ? (fwdS + d) : (bwdS + d - 600);
    size_t rbase = (size_t)bi * SS * 600;
    float a0 = 0.f, a1 = 0.f, a2 = 0.f, a3 = 0.f;
#pragma unroll 4
    for (int s = 0; s < SS; s += 4) {
        a0 += p_lds[s + 0] * Sb[rbase + (size_t)(s + 0) * 600];
        a1 += p_lds[s + 1] * Sb[rbase + (size_t)(s + 1) * 600];
        a2 += p_lds[s + 2] * Sb[rbase + (size_t)(s + 2) * 600];
        a3 += p_lds[s + 3] * Sb[rbase + (size_t)(s + 3) * 600];
    }
    (ws + CTX_OFF)[bi * 1200 + d] = (a0 + a1) + (a2 + a3);
}

// ---------------- K3d: g/f gates over cat=[ctx,hs]  (grid 32 x 20)
__global__ __launch_bounds__(256) void attn_gate(const float* __restrict__ Wg,
                                                 const float* __restrict__ bg,
                                                 const float* __restrict__ Wf,
                                                 const float* __restrict__ bf,
                                                 float* __restrict__ ws) {
    __shared__ float cat_lds[2400];
    const int bi = blockIdx.x, ob = blockIdx.y * 60, tid = threadIdx.x;
    const float* ws_ctx = ws + CTX_OFF;
    const float* ws_hs = ws + HS_OFF;
    for (int k = tid; k < 1200; k += 256) {
        cat_lds[k] = ws_ctx[bi * 1200 + k];
        cat_lds[1200 + k] = ws_hs[bi * 1200 + k];
    }
    __syncthreads();
    float* ws_g = ws + GATED_OFF;
    const int wave = tid >> 6, lane = tid & 63;
    for (int i = 0; i < 15; ++i) {
        int o = ob + wave * 15 + i;
        const float* wg = Wg + (size_t)o * D4;
        const float* wf = Wf + (size_t)o * D4;
        float ag = 0.f, af = 0.f;
        for (int k = lane; k < D4; k += 64) {
            float c = cat_lds[k];
            ag += c * wg[k];
            af += c * wf[k];
        }
        for (int off = 32; off > 0; off >>= 1) {
            ag += __shfl_down(ag, off);
            af += __shfl_down(af, off);
        }
        if (lane == 0) {
            float g = 1.f / (1.f + expf(-(ag + bg[o])));
            float f = tanhf(af + bf[o]);
            ws_g[bi * 1200 + o] = g * f + (1.f - g) * cat_lds[1200 + o];
        }
    }
}

// ---------------- K3e: broadcast gated -> attn output (overwrites the states scratch)
__global__ void bcast_attn(const float* __restrict__ ws, float* __restrict__ outp) {
    int idx = blockIdx.x * 256 + threadIdx.x;     // float4 index, exactly 3686400
    const float4* g4 = (const float4*)(ws + GATED_OFF);
    float4* o4 = (float4*)outp;
    int row = idx / 300;          // bi*384+si
    int d4 = idx - row * 300;
    int bi = row / SS;
    o4[300 + idx] = g4[bi * 300 + d4];
}

extern "C" void kernel_launch(void* const* d_in, const int* in_sizes, int n_in,
                              void* d_out, int out_size, void* d_ws, size_t ws_size,
                              hipStream_t stream) {
    const float* ctx   = (const float*)d_in[0];
    const int*   tags  = (const int*)d_in[1];
    const float* bio   = (const float*)d_in[2];
    const float* W_ih  = (const float*)d_in[3];
    const float* b_ih  = (const float*)d_in[4];
    const float* W_hh  = (const float*)d_in[5];
    const float* b_hh  = (const float*)d_in[6];
    const float* W_lin = (const float*)d_in[7];
    const float* b_lin = (const float*)d_in[8];
    const float* W_g   = (const float*)d_in[9];
    const float* b_g   = (const float*)d_in[10];
    const float* W_f   = (const float*)d_in[11];
    const float* b_f   = (const float*)d_in[12];
    float* out = (float*)d_out;
    float* ws  = (float*)d_ws;

    // Poison the full state-history region (it doubles as the scan's sync
    // medium: sentinel = "not yet produced"); zero the readiness counters.
    hipMemsetAsync(out + 1200, 0xAA, (size_t)2 * TT * 600 * sizeof(float), stream);
    hipMemsetAsync(ws + COUNT_OFF, 0, (size_t)2 * 512 * sizeof(unsigned), stream);

    build_emb<<<(TT * INP_P + 255) / 256, 256, 0, stream>>>(ctx, tags, bio, ws + EMB_OFF);
    pad_wih<<<(GG * INP_P + 255) / 256, 256, 0, stream>>>(W_ih, ws + WP_OFF);
    gemm_gi<<<dim3(TT / 64, 29), 256, 0, stream>>>(ws + EMB_OFF, ws + WP_OFF, b_ih, ws + GI_OFF);
    gru_scan<<<2 * NWG, 256, 0, stream>>>(ws + GI_OFF, W_hh, b_hh, ws, out);
    attn_qs<<<dim3(BB, 20), 256, 0, stream>>>(W_lin, b_lin, out, ws);
    attn_logits<<<BB, 256, 0, stream>>>(out, ws);
    attn_ctxv<<<dim3(BB, 5), 256, 0, stream>>>(out, ws);
    attn_gate<<<dim3(BB, 20), 256, 0, stream>>>(W_g, b_g, W_f, b_f, ws);
    bcast_attn<<<14400, 256, 0, stream>>>(ws, out);
}

// Round 8
// 22075.099 us; speedup vs baseline: 1.2024x; 1.2024x over previous
//
#include <hip/hip_runtime.h>
#include <math.h>

// Problem constants
#define TT    12288            // B*S flattened scan length
#define HH    600
#define GG    1800             // 3*H
#define INP   303
#define INP_P 304              // padded for float4 alignment
#define BB    32
#define SS    384
#define D2    1200             // 2H
#define D4    2400             // 4H (cat dim)

// Scan partitioning: 75 workgroups per chain, 8 outputs each
#define NWG  75
#define JPW  8
#define WROW 608               // LDS row pad: 608 % 32 == 0 -> row base bank 0

// ws layout (float offsets)
#define EMB_OFF    0ull                // also reused as P_OFF after gemm_gi consumes emb
#define WP_OFF     3735552ull          // 12288*304
#define GI_OFF     4282752ull          // + 1800*304
#define HS_OFF     26403808ull
#define Q_OFF      26442208ull
#define CTX_OFF    26480608ull
#define GATED_OFF  26519008ull
#define EXCH_OFF   26557408ull         // 2 chains * 2 slots * 600 pairs * 8B = 19200B
#define P_OFF      0ull                // probs (32*384) — emb region is dead by then

typedef unsigned long long ull;

// ---------------- K0: build padded emb = [bio_emb[tag], context], and padded W_ih
__global__ void build_emb(const float* __restrict__ ctx, const int* __restrict__ tags,
                          const float* __restrict__ bio, float* __restrict__ emb) {
    int idx = blockIdx.x * 256 + threadIdx.x;
    if (idx >= TT * INP_P) return;
    int row = idx / INP_P;
    int c = idx - row * INP_P;
    float v;
    if (c < 3)        v = bio[tags[row] * 3 + c];
    else if (c < INP) v = ctx[(size_t)row * 300 + (c - 3)];
    else              v = 0.f;
    emb[idx] = v;
}

__global__ void pad_wih(const float* __restrict__ W, float* __restrict__ Wp) {
    int idx = blockIdx.x * 256 + threadIdx.x;
    if (idx >= GG * INP_P) return;
    int r = idx / INP_P, c = idx - r * INP_P;
    Wp[idx] = (c < INP) ? W[(size_t)r * INP + c] : 0.f;
}

// ---------------- K1: gi = emb @ W_ih^T + b_ih   (fp32 tiled GEMM, 64x64 tile, BK=16)
__global__ __launch_bounds__(256) void gemm_gi(const float* __restrict__ A,
                                               const float* __restrict__ Bw,
                                               const float* __restrict__ bias,
                                               float* __restrict__ C) {
    __shared__ float As[16][68];
    __shared__ float Bs[16][68];
    const int tid = threadIdx.x;
    const int bm = blockIdx.x, bn = blockIdx.y;
    const int tx = tid & 15, ty = tid >> 4;
    const int lm = tid >> 2;          // 0..63
    const int lk = (tid & 3) * 4;     // 0,4,8,12
    const int gbase = bn * 64;
    float acc[4][4] = {};
    for (int k0 = 0; k0 < INP_P; k0 += 16) {
        float4 av = *(const float4*)(A + (size_t)(bm * 64 + lm) * INP_P + k0 + lk);
        int grow = gbase + lm;
        float4 bv = make_float4(0.f, 0.f, 0.f, 0.f);
        if (grow < GG) bv = *(const float4*)(Bw + (size_t)grow * INP_P + k0 + lk);
        As[lk + 0][lm] = av.x; As[lk + 1][lm] = av.y; As[lk + 2][lm] = av.z; As[lk + 3][lm] = av.w;
        Bs[lk + 0][lm] = bv.x; Bs[lk + 1][lm] = bv.y; Bs[lk + 2][lm] = bv.z; Bs[lk + 3][lm] = bv.w;
        __syncthreads();
#pragma unroll
        for (int kk = 0; kk < 16; ++kk) {
            float4 a4 = *(const float4*)&As[kk][tx * 4];
            float4 b4 = *(const float4*)&Bs[kk][ty * 4];
            acc[0][0] += a4.x * b4.x; acc[0][1] += a4.x * b4.y; acc[0][2] += a4.x * b4.z; acc[0][3] += a4.x * b4.w;
            acc[1][0] += a4.y * b4.x; acc[1][1] += a4.y * b4.y; acc[1][2] += a4.y * b4.z; acc[1][3] += a4.y * b4.w;
            acc[2][0] += a4.z * b4.x; acc[2][1] += a4.z * b4.y; acc[2][2] += a4.z * b4.z; acc[2][3] += a4.z * b4.w;
            acc[3][0] += a4.w * b4.x; acc[3][1] += a4.w * b4.y; acc[3][2] += a4.w * b4.z; acc[3][3] += a4.w * b4.w;
        }
        __syncthreads();
    }
    int g0 = gbase + ty * 4;
    if (g0 < GG) {
        float4 bi4 = *(const float4*)(bias + g0);
#pragma unroll
        for (int i = 0; i < 4; ++i) {
            float4 v = make_float4(acc[i][0] + bi4.x, acc[i][1] + bi4.y,
                                   acc[i][2] + bi4.z, acc[i][3] + bi4.w);
            *(float4*)(C + (size_t)(bm * 64 + tx * 4 + i) * GG + g0) = v;
        }
    }
}

// ---------------- K2: the two sequential GRU scans.
// Sync = tagged parity exchange (2-hop: store -> poll-hit IS the data load).
// exch[chain][slot=t&1][v] is an 8B pair (hi=tag t, lo=fp32 h[v]); tags
// self-validate so no memset / sentinel / counter is needed. Each wg's 8
// outputs share one 64B line; consumer lane L polls the 4 pairs 4L..4L+3
// (single line, 4 independent 8B atomic loads -> one waitcnt) => only ~150
// requesters per line chip-wide (round-5 protocol had 600-1200: hot-bank
// queueing). Overwrite safety: a wg writing slot t has tag-verified all of
// h_{t-1}, whose producers verified all of h_{t-2} -> nothing still reads the
// h_{t-2} being overwritten. History stores are plain cached stores (sync no
// longer rides on them); epilogue kernels see them via kernel-boundary flush.
// One barrier/step; h double-buffered in LDS; gi pipelined one step ahead;
// weights in bank-aligned LDS.
__global__ __launch_bounds__(256) void gru_scan(const float* __restrict__ gi,
                                                const float* __restrict__ Whh,
                                                const float* __restrict__ bhh,
                                                float* __restrict__ ws,
                                                float* __restrict__ out) {
    __shared__ __align__(16) float w_lds[JPW * 3 * WROW];   // 58,368 B
    __shared__ __align__(16) float h_lds[2][WROW];          //  4,864 B

    const int tid = threadIdx.x;
    const int chain = blockIdx.x / NWG;   // 0 = fwd, 1 = bwd
    const int wg = blockIdx.x % NWG;
    const int j0 = wg * JPW;
    const int wave = tid >> 6;
    const int lane = tid & 63;
    const int half = lane >> 5;
    const int s = lane & 31;              // sub-lane within 32-lane group
    const int j = wave * 2 + half;        // output 0..7 within wg
    const int jg = j0 + j;                // global hidden index

    float* statesOut = out + 1200 + (size_t)chain * TT * 600;
    ull* exch = (ull*)(ws + EXCH_OFF) + (size_t)chain * 1200;   // [2 slots][600]

    // ---- one-time: W_hh slice into LDS. w_lds[(j*3+g)*WROW + c]
    for (int q = tid; q < JPW * 3 * 150; q += 256) {   // 150 float4 per row
        int row = q / 150, c4 = (q - row * 150) * 4;
        int jj = row / 3, g = row - jj * 3;
        *(float4*)&w_lds[row * WROW + c4] =
            *(const float4*)(Whh + (size_t)(g * 600 + j0 + jj) * 600 + c4);
    }
    float b_r = 0.f, b_z = 0.f, b_n = 0.f;
    if (s == 0) { b_r = bhh[jg]; b_z = bhh[600 + jg]; b_n = bhh[1200 + jg]; }
    for (int i = tid; i < 2 * WROW; i += 256) h_lds[0][i] = 0.f;
    __syncthreads();

    // gi pipeline: load row(0) now, issue row(t+1) inside the loop
    float gr_c = 0.f, gz_c = 0.f, gn_c = 0.f;
    int si = 0, bi = 0;
    if (s == 0) {
        int r0 = (chain == 0) ? 0 : (SS - 1);
        const float* gp = gi + (size_t)r0 * GG + jg;
        gr_c = gp[0]; gz_c = gp[600]; gn_c = gp[1200];
    }

    float h_own = 0.f;                    // h_{t-1}[jg], kept by s==0 lanes

    for (int t = 0; t < TT; ++t) {
        const int slot = t & 1;
        if (t > 0) {
            if (tid < 150) {
                // poll own 4 pairs (one 64B line); tag match == data valid
                const ull* ep = exch + (size_t)((t - 1) & 1) * 600 + tid * 4;
                const unsigned tg = (unsigned)(t - 1);
                ull u0, u1, u2, u3;
                for (;;) {
                    u0 = __hip_atomic_load(ep + 0, __ATOMIC_RELAXED, __HIP_MEMORY_SCOPE_AGENT);
                    u1 = __hip_atomic_load(ep + 1, __ATOMIC_RELAXED, __HIP_MEMORY_SCOPE_AGENT);
                    u2 = __hip_atomic_load(ep + 2, __ATOMIC_RELAXED, __HIP_MEMORY_SCOPE_AGENT);
                    u3 = __hip_atomic_load(ep + 3, __ATOMIC_RELAXED, __HIP_MEMORY_SCOPE_AGENT);
                    if ((unsigned)(u0 >> 32) == tg && (unsigned)(u1 >> 32) == tg &&
                        (unsigned)(u2 >> 32) == tg && (unsigned)(u3 >> 32) == tg) break;
                    __builtin_amdgcn_s_sleep(1);
                }
                float4 hv = make_float4(__uint_as_float((unsigned)u0),
                                        __uint_as_float((unsigned)u1),
                                        __uint_as_float((unsigned)u2),
                                        __uint_as_float((unsigned)u3));
                *(float4*)&h_lds[slot][tid * 4] = hv;
            }
            __syncthreads();              // the ONLY barrier per step
        }
        // issue next step's gi loads (consumed next iteration)
        float gr_n = gr_c, gz_n = gz_c, gn_n = gn_c;
        int si2 = si + 1, bi2 = bi;
        if (si2 == SS) { si2 = 0; ++bi2; }
        if (s == 0 && t + 1 < TT) {
            int rn = (chain == 0) ? (t + 1) : (bi2 * SS + (SS - 1) - si2);
            const float* gp = gi + (size_t)rn * GG + jg;
            gr_n = gp[0]; gz_n = gp[600]; gn_n = gp[1200];
        }
        // matvec: rows {j, 600+j, 1200+j}, lane s covers cols [20s, 20s+20)
        float a0 = 0.f, a1 = 0.f, a2 = 0.f;
        if (s < 30) {
            const float* w0 = &w_lds[(j * 3 + 0) * WROW + s * 20];
            const float* w1 = &w_lds[(j * 3 + 1) * WROW + s * 20];
            const float* w2 = &w_lds[(j * 3 + 2) * WROW + s * 20];
            const float* hp = &h_lds[slot][s * 20];
#pragma unroll
            for (int u = 0; u < 5; ++u) {
                float4 hv = *(const float4*)(hp + u * 4);
                float4 x0 = *(const float4*)(w0 + u * 4);
                float4 x1 = *(const float4*)(w1 + u * 4);
                float4 x2 = *(const float4*)(w2 + u * 4);
                a0 += x0.x * hv.x + x0.y * hv.y + x0.z * hv.z + x0.w * hv.w;
                a1 += x1.x * hv.x + x1.y * hv.y + x1.z * hv.z + x1.w * hv.w;
                a2 += x2.x * hv.x + x2.y * hv.y + x2.z * hv.z + x2.w * hv.w;
            }
        }
#pragma unroll
        for (int off = 16; off > 0; off >>= 1) {
            a0 += __shfl_down(a0, off, 32);
            a1 += __shfl_down(a1, off, 32);
            a2 += __shfl_down(a2, off, 32);
        }
        if (s == 0) {
            float r = 1.f / (1.f + __expf(-(gr_c + a0 + b_r)));
            float z = 1.f / (1.f + __expf(-(gz_c + a1 + b_z)));
            float x = gn_c + r * (a2 + b_n);
            float e = __expf(-2.f * fabsf(x));
            float n = copysignf((1.f - e) / (1.f + e), x);
            float hnew = (1.f - z) * n + z * h_own;
            h_own = hnew;
            // plain cached history store (consumed by epilogue kernels only)
            statesOut[(size_t)t * 600 + jg] = hnew;
            // tagged exchange store: 8B atomic pair (tag, value)
            __hip_atomic_store(exch + (size_t)slot * 600 + jg,
                               ((ull)(unsigned)t << 32) | (ull)__float_as_uint(hnew),
                               __ATOMIC_RELAXED, __HIP_MEMORY_SCOPE_AGENT);
            if (t == TT - 1) out[chain * 600 + jg] = hnew;   // final = [h_f, h_b]
        }
        gr_c = gr_n; gz_c = gz_n; gn_c = gn_n;
        si = si2; bi = bi2;
    }
}

// ---------------- K3a: hs gather + q = hs @ W_lin^T + b_lin  (grid 32 x 20)
__global__ __launch_bounds__(256) void attn_qs(const float* __restrict__ Wlin,
                                               const float* __restrict__ blin,
                                               const float* __restrict__ outp,
                                               float* __restrict__ ws) {
    __shared__ float hs_lds[1200];
    const int bi = blockIdx.x, ob = blockIdx.y * 60, tid = threadIdx.x;
    const float* fwdS = outp + 1200;
    const float* bwdS = outp + 1200 + (size_t)TT * 600;
    size_t row = (size_t)(bi * SS + SS - 1) * 600;
    for (int k = tid; k < 600; k += 256) {
        hs_lds[k] = fwdS[row + k];
        hs_lds[600 + k] = bwdS[row + k];
    }
    __syncthreads();
    if (blockIdx.y == 0) {
        float* ws_hs = ws + HS_OFF;
        for (int k = tid; k < 1200; k += 256) ws_hs[bi * 1200 + k] = hs_lds[k];
    }
    float* ws_q = ws + Q_OFF;
    const int wave = tid >> 6, lane = tid & 63;
    for (int i = 0; i < 15; ++i) {
        int o = ob + wave * 15 + i;
        const float* wr = Wlin + (size_t)o * 1200;
        float acc = 0.f;
        for (int k = lane; k < 1200; k += 64) acc += hs_lds[k] * wr[k];
        for (int off = 32; off > 0; off >>= 1) acc += __shfl_down(acc, off);
        if (lane == 0) ws_q[bi * 1200 + o] = acc + blin[o];
    }
}

// ---------------- K3b: logits + softmax -> probs
__global__ __launch_bounds__(256) void attn_logits(const float* __restrict__ outp,
                                                   float* __restrict__ ws) {
    __shared__ float q_lds[1200];
    __shared__ float p_lds[SS];
    __shared__ float red[8];
    const int bi = blockIdx.x, tid = threadIdx.x;
    const float* fwdS = outp + 1200;
    const float* bwdS = outp + 1200 + (size_t)TT * 600;
    const float* ws_q = ws + Q_OFF;
    for (int k = tid; k < 1200; k += 256) q_lds[k] = ws_q[bi * 1200 + k];
    __syncthreads();
    const int wave = tid >> 6, lane = tid & 63;
    for (int s = wave; s < SS; s += 4) {
        size_t base = (size_t)(bi * SS + s) * 600;
        float acc = 0.f;
        for (int k = lane; k < 600; k += 64)
            acc += q_lds[k] * fwdS[base + k] + q_lds[600 + k] * bwdS[base + k];
        for (int off = 32; off > 0; off >>= 1) acc += __shfl_down(acc, off);
        if (lane == 0) p_lds[s] = acc;
    }
    __syncthreads();
    float m = -1e30f;
    for (int i = tid; i < SS; i += 256) m = fmaxf(m, p_lds[i]);
    for (int off = 32; off > 0; off >>= 1) m = fmaxf(m, __shfl_down(m, off));
    if (lane == 0) red[wave] = m;
    __syncthreads();
    m = fmaxf(fmaxf(red[0], red[1]), fmaxf(red[2], red[3]));
    float ssum = 0.f;
    for (int i = tid; i < SS; i += 256) ssum += expf(p_lds[i] - m);
    for (int off = 32; off > 0; off >>= 1) ssum += __shfl_down(ssum, off);
    __syncthreads();
    if (lane == 0) red[wave] = ssum;
    __syncthreads();
    ssum = red[0] + red[1] + red[2] + red[3];
    float inv = 1.f / ssum;
    float* ws_p = ws + P_OFF;
    for (int i = tid; i < SS; i += 256) ws_p[bi * SS + i] = expf(p_lds[i] - m) * inv;
}

// ---------------- K3c: ctx = probs @ states  (grid 32 x 5, 240 threads active)
__global__ __launch_bounds__(256) void attn_ctxv(const float* __restrict__ outp,
                                                 float* __restrict__ ws) {
    __shared__ float p_lds[SS];
    const int bi = blockIdx.x, d0 = blockIdx.y * 240, tid = threadIdx.x;
    const float* ws_p = ws + P_OFF;
    for (int k = tid; k < SS; k += 256) p_lds[k] = ws_p[bi * SS + k];
    __syncthreads();
    if (tid >= 240) return;
    const int d = d0 + tid;
    const float* fwdS = outp + 1200;
    const float* bwdS = outp + 1200 + (size_t)TT * 600;
    const float* Sb = (d < 600) ? (fwdS + d) : (bwdS + d - 600);
    size_t rbase = (size_t)bi * SS * 600;
    float a0 = 0.f, a1 = 0.f, a2 = 0.f, a3 = 0.f;
#pragma unroll 4
    for (int s = 0; s < SS; s += 4) {
        a0 += p_lds[s + 0] * Sb[rbase + (size_t)(s + 0) * 600];
        a1 += p_lds[s + 1] * Sb[rbase + (size_t)(s + 1) * 600];
        a2 += p_lds[s + 2] * Sb[rbase + (size_t)(s + 2) * 600];
        a3 += p_lds[s + 3] * Sb[rbase + (size_t)(s + 3) * 600];
    }
    (ws + CTX_OFF)[bi * 1200 + d] = (a0 + a1) + (a2 + a3);
}

// ---------------- K3d: g/f gates over cat=[ctx,hs]  (grid 32 x 20)
__global__ __launch_bounds__(256) void attn_gate(const float* __restrict__ Wg,
                                                 const float* __restrict__ bg,
                                                 const float* __restrict__ Wf,
                                                 const float* __restrict__ bf,
                                                 float* __restrict__ ws) {
    __shared__ float cat_lds[2400];
    const int bi = blockIdx.x, ob = blockIdx.y * 60, tid = threadIdx.x;
    const float* ws_ctx = ws + CTX_OFF;
    const float* ws_hs = ws + HS_OFF;
    for (int k = tid; k < 1200; k += 256) {
        cat_lds[k] = ws_ctx[bi * 1200 + k];
        cat_lds[1200 + k] = ws_hs[bi * 1200 + k];
    }
    __syncthreads();
    float* ws_g = ws + GATED_OFF;
    const int wave = tid >> 6, lane = tid & 63;
    for (int i = 0; i < 15; ++i) {
        int o = ob + wave * 15 + i;
        const float* wg = Wg + (size_t)o * D4;
        const float* wf = Wf + (size_t)o * D4;
        float ag = 0.f, af = 0.f;
        for (int k = lane; k < D4; k += 64) {
            float c = cat_lds[k];
            ag += c * wg[k];
            af += c * wf[k];
        }
        for (int off = 32; off > 0; off >>= 1) {
            ag += __shfl_down(ag, off);
            af += __shfl_down(af, off);
        }
        if (lane == 0) {
            float g = 1.f / (1.f + expf(-(ag + bg[o])));
            float f = tanhf(af + bf[o]);
            ws_g[bi * 1200 + o] = g * f + (1.f - g) * cat_lds[1200 + o];
        }
    }
}

// ---------------- K3e: broadcast gated -> attn output (overwrites the states scratch)
__global__ void bcast_attn(const float* __restrict__ ws, float* __restrict__ outp) {
    int idx = blockIdx.x * 256 + threadIdx.x;     // float4 index, exactly 3686400
    const float4* g4 = (const float4*)(ws + GATED_OFF);
    float4* o4 = (float4*)outp;
    int row = idx / 300;          // bi*384+si
    int d4 = idx - row * 300;
    int bi = row / SS;
    o4[300 + idx] = g4[bi * 300 + d4];
}

extern "C" void kernel_launch(void* const* d_in, const int* in_sizes, int n_in,
                              void* d_out, int out_size, void* d_ws, size_t ws_size,
                              hipStream_t stream) {
    const float* ctx   = (const float*)d_in[0];
    const int*   tags  = (const int*)d_in[1];
    const float* bio   = (const float*)d_in[2];
    const float* W_ih  = (const float*)d_in[3];
    const float* b_ih  = (const float*)d_in[4];
    const float* W_hh  = (const float*)d_in[5];
    const float* b_hh  = (const float*)d_in[6];
    const float* W_lin = (const float*)d_in[7];
    const float* b_lin = (const float*)d_in[8];
    const float* W_g   = (const float*)d_in[9];
    const float* b_g   = (const float*)d_in[10];
    const float* W_f   = (const float*)d_in[11];
    const float* b_f   = (const float*)d_in[12];
    float* out = (float*)d_out;
    float* ws  = (float*)d_ws;

    // No memsets needed: the tagged exchange self-validates (poisoned/stale
    // tags never equal the expected step index).
    build_emb<<<(TT * INP_P + 255) / 256, 256, 0, stream>>>(ctx, tags, bio, ws + EMB_OFF);
    pad_wih<<<(GG * INP_P + 255) / 256, 256, 0, stream>>>(W_ih, ws + WP_OFF);
    gemm_gi<<<dim3(TT / 64, 29), 256, 0, stream>>>(ws + EMB_OFF, ws + WP_OFF, b_ih, ws + GI_OFF);
    gru_scan<<<2 * NWG, 256, 0, stream>>>(ws + GI_OFF, W_hh, b_hh, ws, out);
    attn_qs<<<dim3(BB, 20), 256, 0, stream>>>(W_lin, b_lin, out, ws);
    attn_logits<<<BB, 256, 0, stream>>>(out, ws);
    attn_ctxv<<<dim3(BB, 5), 256, 0, stream>>>(out, ws);
    attn_gate<<<dim3(BB, 20), 256, 0, stream>>>(W_g, b_g, W_f, b_f, ws);
    bcast_attn<<<14400, 256, 0, stream>>>(ws, out);
}